// Round 2
// baseline (510.053 us; speedup 1.0000x reference)
//
#include <hip/hip_runtime.h>
#include <hip/hip_fp16.h>

#define DD 192
#define HH 192
#define WW 192
#define NVOX (DD * HH * WW)

#define VPB 2048                  // voxels per block (256 thr x 8)
#define NBLK (NVOX / VPB)         // 3456 blocks
#define NXCD 8
#define BPX (NBLK / NXCD)         // 432 blocks per XCD = 24 z-planes

typedef float f32x4 __attribute__((ext_vector_type(4)));
typedef int   i32x4 __attribute__((ext_vector_type(4)));

// ---- mov fp32 -> fp16 (contiguous, BW-bound, runs once per launch) ----
__global__ __launch_bounds__(256) void conv_fp16(
    const float4* __restrict__ in, int4* __restrict__ out)
{
    const int i = blockIdx.x * 256 + threadIdx.x;
    const float4 a = in[2 * i];
    const float4 b = in[2 * i + 1];
    __half2 h0 = __floats2half2_rn(a.x, a.y);
    __half2 h1 = __floats2half2_rn(a.z, a.w);
    __half2 h2 = __floats2half2_rn(b.x, b.y);
    __half2 h3 = __floats2half2_rn(b.z, b.w);
    int4 o;
    o.x = *(int*)&h0; o.y = *(int*)&h1; o.z = *(int*)&h2; o.w = *(int*)&h3;
    out[i] = o;
}

// nt loads: read-once streams evict-first so L2 keeps the movh z-slab hot
__device__ __forceinline__ f32x4 ntl(const float* p) {
    return __builtin_nontemporal_load((const f32x4*)p);
}
__device__ __forceinline__ i32x4 ntli(const int* p) {
    return __builtin_nontemporal_load((const i32x4*)p);
}

// trilinear sample one voxel directly from fp16 volume (L2-resident slab)
__device__ __forceinline__ void sample_one(
    const __half* __restrict__ movh,
    int gz, int gy, int gx, float dz, float dy, float dx,
    float f, int m, float& sq, float& cnt)
{
    const float z = (float)gz + dz, y = (float)gy + dy, x = (float)gx + dx;
    const float z0f = floorf(z), y0f = floorf(y), x0f = floorf(x);
    const float wz = z - z0f, wy = y - y0f, wx = x - x0f;
    const int z0 = (int)z0f, y0 = (int)y0f, x0 = (int)x0f;
    const int z1 = z0 + 1, y1 = y0 + 1, x1 = x0 + 1;
    const bool zi0 = (unsigned)z0 < DD, zi1 = (unsigned)z1 < DD;
    const bool yi0 = (unsigned)y0 < HH, yi1 = (unsigned)y1 < HH;
    const bool xi0 = (unsigned)x0 < WW, xi1 = (unsigned)x1 < WW;
    const int zc0 = min(max(z0, 0), DD - 1), zc1 = min(max(z1, 0), DD - 1);
    const int yc0 = min(max(y0, 0), HH - 1), yc1 = min(max(y1, 0), HH - 1);
    const int xc0 = min(max(x0, 0), WW - 1), xc1 = min(max(x1, 0), WW - 1);
    const int r00 = (zc0 * HH + yc0) * WW;
    const int r01 = (zc0 * HH + yc1) * WW;
    const int r10 = (zc1 * HH + yc0) * WW;
    const int r11 = (zc1 * HH + yc1) * WW;
    float v000 = __half2float(movh[r00 + xc0]);
    float v001 = __half2float(movh[r00 + xc1]);
    float v010 = __half2float(movh[r01 + xc0]);
    float v011 = __half2float(movh[r01 + xc1]);
    float v100 = __half2float(movh[r10 + xc0]);
    float v101 = __half2float(movh[r10 + xc1]);
    float v110 = __half2float(movh[r11 + xc0]);
    float v111 = __half2float(movh[r11 + xc1]);
    v000 = (zi0 & yi0 & xi0) ? v000 : 0.0f;
    v001 = (zi0 & yi0 & xi1) ? v001 : 0.0f;
    v010 = (zi0 & yi1 & xi0) ? v010 : 0.0f;
    v011 = (zi0 & yi1 & xi1) ? v011 : 0.0f;
    v100 = (zi1 & yi0 & xi0) ? v100 : 0.0f;
    v101 = (zi1 & yi0 & xi1) ? v101 : 0.0f;
    v110 = (zi1 & yi1 & xi0) ? v110 : 0.0f;
    v111 = (zi1 & yi1 & xi1) ? v111 : 0.0f;

    const float c00 = v000 + (v001 - v000) * wx;
    const float c01 = v010 + (v011 - v010) * wx;
    const float c10 = v100 + (v101 - v100) * wx;
    const float c11 = v110 + (v111 - v110) * wx;
    const float c0 = c00 + (c01 - c00) * wy;
    const float c1 = c10 + (c11 - c10) * wy;
    const float warped = c0 + (c1 - c0) * wz;

    const float mm = (m != 0) ? 1.0f : 0.0f;
    const float diff = warped - f;
    sq += diff * diff * mm;
    cnt += mm;
}

// ---- direct-gather kernel: no LDS staging, no barriers, L2 does the reuse ----
// XCD-chunked swizzle: physical block b0 -> XCD b0%8 (HW round-robin), logical
// work L = (b0&7)*432 + (b0>>3), so XCD k owns the contiguous z-slab
// [24k, 24k+24). movh slab + |disp|<=15 halo ~ 2.4-3 MB: fits 4 MB L2/XCD.
__global__ __launch_bounds__(256) void warp_mse_gather(
    const __half* __restrict__ movh,
    const float* __restrict__ vf,
    const float* __restrict__ fix,
    const int* __restrict__ mask,
    float* __restrict__ acc,   // [0]=sum(sq*m), [1]=sum(m), [2]=done ctr
    float* __restrict__ out)
{
    __shared__ float s_sq[4], s_cnt[4];

    const int b0 = blockIdx.x;
    const int L = (b0 & (NXCD - 1)) * BPX + (b0 >> 3);
    const int base = L * VPB + (threadIdx.x << 3);   // 8-aligned, never crosses x-row
    const int row = base / WW;
    const int gx  = base - row * WW;
    const int gy  = row % HH;
    const int gz  = row / HH;

    // all stream loads issued up front (ILP hides L2/HBM latency)
    const f32x4 za = ntl(vf + base),            zb = ntl(vf + base + 4);
    const f32x4 ya = ntl(vf + NVOX + base),     yb = ntl(vf + NVOX + base + 4);
    const f32x4 xa = ntl(vf + 2 * NVOX + base), xb = ntl(vf + 2 * NVOX + base + 4);
    const f32x4 fa = ntl(fix + base),           fb = ntl(fix + base + 4);
    const i32x4 ma = ntli(mask + base),         mb = ntli(mask + base + 4);

    float sq = 0.0f, cnt = 0.0f;
    sample_one(movh, gz, gy, gx + 0, za.x, ya.x, xa.x, fa.x, ma.x, sq, cnt);
    sample_one(movh, gz, gy, gx + 1, za.y, ya.y, xa.y, fa.y, ma.y, sq, cnt);
    sample_one(movh, gz, gy, gx + 2, za.z, ya.z, xa.z, fa.z, ma.z, sq, cnt);
    sample_one(movh, gz, gy, gx + 3, za.w, ya.w, xa.w, fa.w, ma.w, sq, cnt);
    sample_one(movh, gz, gy, gx + 4, zb.x, yb.x, xb.x, fb.x, mb.x, sq, cnt);
    sample_one(movh, gz, gy, gx + 5, zb.y, yb.y, xb.y, fb.y, mb.y, sq, cnt);
    sample_one(movh, gz, gy, gx + 6, zb.z, yb.z, xb.z, fb.z, mb.z, sq, cnt);
    sample_one(movh, gz, gy, gx + 7, zb.w, yb.w, xb.w, fb.w, mb.w, sq, cnt);

    // ---- reduction: wave64 shuffle -> LDS -> one atomic pair per block ----
    #pragma unroll
    for (int off = 32; off > 0; off >>= 1) {
        sq  += __shfl_down(sq, off, 64);
        cnt += __shfl_down(cnt, off, 64);
    }
    const int lane = threadIdx.x & 63;
    const int wid = threadIdx.x >> 6;
    if (lane == 0) { s_sq[wid] = sq; s_cnt[wid] = cnt; }
    __syncthreads();
    if (threadIdx.x == 0) {
        const float bsq  = s_sq[0] + s_sq[1] + s_sq[2] + s_sq[3];
        const float bcnt = s_cnt[0] + s_cnt[1] + s_cnt[2] + s_cnt[3];
        atomicAdd(&acc[0], bsq);
        atomicAdd(&acc[1], bcnt);
        __threadfence();
        const unsigned old = atomicAdd((unsigned*)&acc[2], 1u);
        if (old == NBLK - 1) {
            __threadfence();
            const float s = atomicAdd(&acc[0], 0.0f);
            const float c = atomicAdd(&acc[1], 0.0f);
            out[0] = s / fmaxf(c, 1.0f);
        }
    }
}

// ---- emergency fallback (ws too small): simple per-voxel fp32 kernel ----
__global__ __launch_bounds__(256) void warp_mse_simple(
    const float* __restrict__ mov, const float* __restrict__ vf,
    const float* __restrict__ fix, const int* __restrict__ mask,
    float* __restrict__ acc)
{
    const int idx = blockIdx.x * 256 + threadIdx.x;
    float sq = 0.0f, cnt = 0.0f;
    if (idx < NVOX) {
        const int w = idx % WW;
        const int t = idx / WW;
        const int h = t % HH;
        const int d = t / HH;
        const float z = (float)d + vf[idx];
        const float y = (float)h + vf[NVOX + idx];
        const float x = (float)w + vf[2 * NVOX + idx];
        const float z0f = floorf(z), y0f = floorf(y), x0f = floorf(x);
        const float wz = z - z0f, wy = y - y0f, wx = x - x0f;
        const int z0 = (int)z0f, y0 = (int)y0f, x0 = (int)x0f;
        const int z1 = z0 + 1, y1 = y0 + 1, x1 = x0 + 1;
        const bool zi0 = (unsigned)z0 < DD, zi1 = (unsigned)z1 < DD;
        const bool yi0 = (unsigned)y0 < HH, yi1 = (unsigned)y1 < HH;
        const bool xi0 = (unsigned)x0 < WW, xi1 = (unsigned)x1 < WW;
        auto ld = [&](int iz, int iy, int ix, bool ok) -> float {
            return ok ? mov[(iz * HH + iy) * WW + ix] : 0.0f;
        };
        const float v000 = ld(z0, y0, x0, zi0 & yi0 & xi0);
        const float v001 = ld(z0, y0, x1, zi0 & yi0 & xi1);
        const float v010 = ld(z0, y1, x0, zi0 & yi1 & xi0);
        const float v011 = ld(z0, y1, x1, zi0 & yi1 & xi1);
        const float v100 = ld(z1, y0, x0, zi1 & yi0 & xi0);
        const float v101 = ld(z1, y0, x1, zi1 & yi0 & xi1);
        const float v110 = ld(z1, y1, x0, zi1 & yi1 & xi0);
        const float v111 = ld(z1, y1, x1, zi1 & yi1 & xi1);
        const float c00 = v000 + (v001 - v000) * wx;
        const float c01 = v010 + (v011 - v010) * wx;
        const float c10 = v100 + (v101 - v100) * wx;
        const float c11 = v110 + (v111 - v110) * wx;
        const float c0 = c00 + (c01 - c00) * wy;
        const float c1 = c10 + (c11 - c10) * wy;
        const float warped = c0 + (c1 - c0) * wz;
        const float m = (mask[idx] != 0) ? 1.0f : 0.0f;
        const float diff = warped - fix[idx];
        sq = diff * diff * m;
        cnt = m;
    }
    #pragma unroll
    for (int off = 32; off > 0; off >>= 1) {
        sq  += __shfl_down(sq, off, 64);
        cnt += __shfl_down(cnt, off, 64);
    }
    __shared__ float s_sq[4], s_cnt[4];
    const int lane = threadIdx.x & 63, wid = threadIdx.x >> 6;
    if (lane == 0) { s_sq[wid] = sq; s_cnt[wid] = cnt; }
    __syncthreads();
    if (threadIdx.x == 0) {
        atomicAdd(&acc[0], s_sq[0] + s_sq[1] + s_sq[2] + s_sq[3]);
        atomicAdd(&acc[1], s_cnt[0] + s_cnt[1] + s_cnt[2] + s_cnt[3]);
    }
}

__global__ void warp_mse_finalize(const float* __restrict__ acc, float* __restrict__ out) {
    out[0] = acc[0] / fmaxf(acc[1], 1.0f);
}

extern "C" void kernel_launch(void* const* d_in, const int* in_sizes, int n_in,
                              void* d_out, int out_size, void* d_ws, size_t ws_size,
                              hipStream_t stream) {
    const float* mov  = (const float*)d_in[0];
    const float* vf   = (const float*)d_in[1];
    const float* fix  = (const float*)d_in[2];
    const int*   mask = (const int*)d_in[3];
    float* acc = (float*)d_ws;
    float* out = (float*)d_out;

    // [0,16): acc + done ctr; [256,...): movh
    hipMemsetAsync(d_ws, 0, 256, stream);

    const size_t need = 256 + (size_t)NVOX * 2;
    if (ws_size >= need) {
        __half* movh = (__half*)((char*)d_ws + 256);
        conv_fp16<<<NVOX / (256 * 8), 256, 0, stream>>>(
            (const float4*)mov, (int4*)movh);
        warp_mse_gather<<<NBLK, 256, 0, stream>>>(movh, vf, fix, mask, acc, out);
    } else {
        warp_mse_simple<<<(NVOX + 255) / 256, 256, 0, stream>>>(mov, vf, fix, mask, acc);
        warp_mse_finalize<<<1, 1, 0, stream>>>(acc, out);
    }
}

// Round 3
// 246.723 us; speedup vs baseline: 2.0673x; 2.0673x over previous
//
#include <hip/hip_runtime.h>
#include <hip/hip_fp16.h>

#define DD 192
#define HH 192
#define WW 192
#define NVOX (DD * HH * WW)

// 16x16x16 tiles, halo 8: fp16 region x32 [-8,+24), y33 [-8,+25), z33 [-8,+25)
#define RSX 32
#define RSY 33
#define RSZ 33
#define ROWD 16                    // dwords per x-row (32 halves)
#define SLABD (RSY * ROWD)         // 528 dwords per z-slab
#define RTOTH (RSX * RSY * RSZ)    // 34848 halves = 69696 B per buffer
#define RTOTD (RTOTH / 2)
#define NCHUNK (RTOTH / 8)         // 4356 16B DMA chunks
#define CHSLAB (RSY * 4)           // 132 chunks per z-slab
#define NT 1024
#define NROUND ((NCHUNK + NT - 1) / NT)   // 5 DMA rounds
#define NTILE 1728                 // 12^3
#define GRID 256                   // persistent: 1 block per CU

#define AS1 __attribute__((address_space(1)))
#define AS3 __attribute__((address_space(3)))

// counted vmcnt: loads stay in flight across raw barriers (T3/T4 pattern)
#define WAITCNT(n) asm volatile("s_waitcnt vmcnt(" #n ")" ::: "memory")

typedef float f32x4 __attribute__((ext_vector_type(4)));
typedef int   i32x4 __attribute__((ext_vector_type(4)));

// ---- mov fp32 -> fp16 (contiguous, BW-bound, runs once per launch) ----
__global__ __launch_bounds__(256) void conv_fp16(
    const float4* __restrict__ in, int4* __restrict__ out)
{
    const int i = blockIdx.x * 256 + threadIdx.x;
    const float4 a = in[2 * i];
    const float4 b = in[2 * i + 1];
    __half2 h0 = __floats2half2_rn(a.x, a.y);
    __half2 h1 = __floats2half2_rn(a.z, a.w);
    __half2 h2 = __floats2half2_rn(b.x, b.y);
    __half2 h3 = __floats2half2_rn(b.z, b.w);
    int4 o;
    o.x = *(int*)&h0; o.y = *(int*)&h1; o.z = *(int*)&h2; o.w = *(int*)&h3;
    out[i] = o;
}

struct Streams { f32x4 dz, dy, dx, f; i32x4 m; };

__device__ __forceinline__ void tile_coords(int n, int& tx, int& ty, int& tz) {
    tx = n / 144;
    const int r = n - tx * 144;
    ty = r / 12;
    tz = r - ty * 12;
}

// issue async DMA of one tile's fp16 region; OOB chunks redirected to zbuf.
// Per-wave vmem instruction count: 4 or 5 (round 4 is partial) — the counted
// vmcnt waits below are derived to be safe for both.
__device__ __forceinline__ void stage_tile(
    const ushort* __restrict__ movh, const ushort* __restrict__ zbuf,
    uint* sbufd, int x_lo, int y_lo, int z_lo, int tid)
{
    ushort* sbuf = (ushort*)sbufd;
    #pragma unroll
    for (int i = 0; i < NROUND; ++i) {
        const int q = tid + i * NT;
        if (q < NCHUNK) {
            const int rz = q / CHSLAB;
            const int rem = q - rz * CHSLAB;
            const int ry = rem >> 2;
            const int k  = rem & 3;
            const int gz = z_lo + rz, gy = y_lo + ry, gx = x_lo + 8 * k;
            const bool valid = ((unsigned)gz < DD) & ((unsigned)gy < HH) &
                               ((unsigned)gx < WW);
            const ushort* src = valid ? (movh + ((gz * HH + gy) * WW + gx)) : zbuf;
            const int qb = i * NT + (tid & ~63);    // wave-uniform chunk base
            __builtin_amdgcn_global_load_lds((AS1 void*)src,
                                             (AS3 void*)(sbuf + 8 * qb), 16, 0, 0);
        }
    }
}

// nontemporal: read-once streams evict-first so L2 keeps staged halos for the
// 52% z-overlap between consecutive tiles on the same CU.
__device__ __forceinline__ Streams prefetch_streams(
    const float* __restrict__ vf, const float* __restrict__ fix,
    const int* __restrict__ mask, int base)
{
    Streams s;
    s.dz = __builtin_nontemporal_load((const f32x4*)(vf + base));
    s.dy = __builtin_nontemporal_load((const f32x4*)(vf + NVOX + base));
    s.dx = __builtin_nontemporal_load((const f32x4*)(vf + 2 * NVOX + base));
    s.f  = __builtin_nontemporal_load((const f32x4*)(fix + base));
    s.m  = __builtin_nontemporal_load((const i32x4*)(mask + base));
    return s;
}

// trilinear sample one voxel from the fp16 LDS buffer (R5/R7-proven structure)
__device__ __forceinline__ void sample_accum(
    const uint* sdw, const float* __restrict__ mov,
    int gz, int gy, int gx, float dz, float dy, float dx,
    float f, int m, int x_lo, int y_lo, int z_lo,
    float& sq, float& cnt)
{
    const float z = (float)gz + dz, y = (float)gy + dy, x = (float)gx + dx;
    const float z0f = floorf(z), y0f = floorf(y), x0f = floorf(x);
    const float wz = z - z0f, wy = y - y0f, wx = x - x0f;
    const int z0 = (int)z0f, y0 = (int)y0f, x0 = (int)x0f;
    const int z0l = z0 - z_lo, y0l = y0 - y_lo, x0l = x0 - x_lo;
    const bool inbox = ((unsigned)z0l < RSZ - 1) & ((unsigned)y0l < RSY - 1) &
                       ((unsigned)x0l < RSX - 1);

    float v000, v001, v010, v011, v100, v101, v110, v111;
    if (inbox) {
        const int o = z0l * SLABD + y0l * ROWD + (x0l >> 1);
        const bool odd = (x0l & 1) != 0;
        const uint a00 = sdw[o];
        const uint b00 = sdw[o + 1];
        const uint a01 = sdw[o + ROWD];
        const uint b01 = sdw[o + ROWD + 1];
        const uint a10 = sdw[o + SLABD];
        const uint b10 = sdw[o + SLABD + 1];
        const uint a11 = sdw[o + SLABD + ROWD];
        const uint b11 = sdw[o + SLABD + ROWD + 1];
        auto pr = [&](uint A, uint B, float& l, float& r) {
            const float2 fa = __half22float2(*(const __half2*)&A);
            const float fb = __low2float(*(const __half2*)&B);
            l = odd ? fa.y : fa.x;
            r = odd ? fb   : fa.y;
        };
        pr(a00, b00, v000, v001);
        pr(a01, b01, v010, v011);
        pr(a10, b10, v100, v101);
        pr(a11, b11, v110, v111);
    } else {
        // rare (~2% of voxels): beyond halo — fp32 global fallback
        const int z1 = z0 + 1, y1 = y0 + 1, x1 = x0 + 1;
        const bool zi0 = (unsigned)z0 < DD, zi1 = (unsigned)z1 < DD;
        const bool yi0 = (unsigned)y0 < HH, yi1 = (unsigned)y1 < HH;
        const bool xi0 = (unsigned)x0 < WW, xi1 = (unsigned)x1 < WW;
        auto ld = [&](int iz, int iy, int ix, bool ok) -> float {
            return ok ? mov[(iz * HH + iy) * WW + ix] : 0.0f;
        };
        v000 = ld(z0, y0, x0, zi0 & yi0 & xi0);
        v001 = ld(z0, y0, x1, zi0 & yi0 & xi1);
        v010 = ld(z0, y1, x0, zi0 & yi1 & xi0);
        v011 = ld(z0, y1, x1, zi0 & yi1 & xi1);
        v100 = ld(z1, y0, x0, zi1 & yi0 & xi0);
        v101 = ld(z1, y0, x1, zi1 & yi0 & xi1);
        v110 = ld(z1, y1, x0, zi1 & yi1 & xi0);
        v111 = ld(z1, y1, x1, zi1 & yi1 & xi1);
    }

    const float c00 = v000 + (v001 - v000) * wx;
    const float c01 = v010 + (v011 - v010) * wx;
    const float c10 = v100 + (v101 - v100) * wx;
    const float c11 = v110 + (v111 - v110) * wx;
    const float c0 = c00 + (c01 - c00) * wy;
    const float c1 = c10 + (c11 - c10) * wy;
    const float warped = c0 + (c1 - c0) * wz;

    const float mm = (m != 0) ? 1.0f : 0.0f;
    const float diff = warped - f;
    sq += diff * diff * mm;
    cnt += mm;
}

// ---- persistent pipelined kernel: double-buffered LDS, counted-vmcnt ----
// Key change vs the 107 us version: __syncthreads (= s_waitcnt vmcnt(0) +
// s_barrier) is replaced by raw barriers + counted vmcnt, so tile k+2's DMA
// is ALREADY in flight while waiting for tile k+1's DMA — no burst-gap.
__global__ __launch_bounds__(NT) void warp_mse_persist(
    const ushort* __restrict__ movh,
    const float* __restrict__ mov,
    const float* __restrict__ vf,
    const float* __restrict__ fix,
    const int* __restrict__ mask,
    const ushort* __restrict__ zbuf,
    float* __restrict__ acc,   // [0]=sum(sq*m), [1]=sum(m), [2]=done ctr
    float* __restrict__ out)
{
    __shared__ uint sbufd[2][RTOTD];   // 2 x 69.7 KB fp16 regions
    __shared__ float s_sq[16], s_cnt[16];

    const int tid = threadIdx.x;
    const int b = blockIdx.x;
    // blocks 0..191: 7 tiles; 192..255: 6 tiles (tile order: z fastest -> L2 reuse)
    const int start = b * 6 + min(b, 192);
    const int cnt_t = 6 + (b < 192 ? 1 : 0);

    // thread -> x-quad: lxg (tid&3)*4, ly (tid>>2)&15, lz tid>>6
    const int lxg = (tid & 3) * 4;
    const int ly  = (tid >> 2) & 15;
    const int lz  = tid >> 6;

    float sq = 0.0f, cntm = 0.0f;

    // ---- prologue: stage tiles start, start+1; streams for both ----
    int tx, ty, tz;
    tile_coords(start, tx, ty, tz);
    stage_tile(movh, zbuf, sbufd[0], tx * 16 - 8, ty * 16 - 8, tz * 16 - 8, tid);
    Streams Scur = prefetch_streams(vf, fix, mask,
        ((tz * 16 + lz) * HH + ty * 16 + ly) * WW + tx * 16 + lxg);
    Streams Snxt = Scur;
    if (cnt_t > 1) {
        int nx, ny, nz;
        tile_coords(start + 1, nx, ny, nz);
        stage_tile(movh, zbuf, sbufd[1], nx * 16 - 8, ny * 16 - 8, nz * 16 - 8, tid);
        Snxt = prefetch_streams(vf, fix, mask,
            ((nz * 16 + lz) * HH + ny * 16 + ly) * WW + nx * 16 + lxg);
        // issued after stage(0): streams(0)[5] + stage(1)[>=4] + streams(1)[5] >= 14
        WAITCNT(14);
    } else {
        WAITCNT(5);
    }
    __builtin_amdgcn_s_barrier();
    __builtin_amdgcn_sched_barrier(0);

    for (int k = 0; k < cnt_t; ++k) {
        const int cur = k & 1;
        int cx, cy, cz;
        tile_coords(start + k, cx, cy, cz);
        const int x_lo = cx * 16 - 8, y_lo = cy * 16 - 8, z_lo = cz * 16 - 8;
        const int gz = cz * 16 + lz, gy = cy * 16 + ly, gx0 = cx * 16 + lxg;
        const uint* sdw = sbufd[cur];

        sample_accum(sdw, mov, gz, gy, gx0,     Scur.dz.x, Scur.dy.x, Scur.dx.x,
                     Scur.f.x, Scur.m.x, x_lo, y_lo, z_lo, sq, cntm);
        sample_accum(sdw, mov, gz, gy, gx0 + 1, Scur.dz.y, Scur.dy.y, Scur.dx.y,
                     Scur.f.y, Scur.m.y, x_lo, y_lo, z_lo, sq, cntm);
        sample_accum(sdw, mov, gz, gy, gx0 + 2, Scur.dz.z, Scur.dy.z, Scur.dx.z,
                     Scur.f.z, Scur.m.z, x_lo, y_lo, z_lo, sq, cntm);
        sample_accum(sdw, mov, gz, gy, gx0 + 3, Scur.dz.w, Scur.dy.w, Scur.dx.w,
                     Scur.f.w, Scur.m.w, x_lo, y_lo, z_lo, sq, cntm);

        if (k + 1 < cnt_t) {
            __builtin_amdgcn_sched_barrier(0);
            __builtin_amdgcn_s_barrier();      // all waves done reading sbufd[cur]
            Streams Snew = Snxt;
            if (k + 2 < cnt_t) {
                int nx, ny, nz;
                tile_coords(start + k + 2, nx, ny, nz);
                // issue k+2 DMA + streams FIRST, then wait only for k+1:
                stage_tile(movh, zbuf, sbufd[cur],
                           nx * 16 - 8, ny * 16 - 8, nz * 16 - 8, tid);
                Snew = prefetch_streams(vf, fix, mask,
                    ((nz * 16 + lz) * HH + ny * 16 + ly) * WW + nx * 16 + lxg);
                // issued after stage(k+1): streams(k+1)[5] + stage(k+2)[>=4]
                //                        + streams(k+2)[5] >= 14
                WAITCNT(14);
            } else {
                // issued after stage(k+1): streams(k+1)[5]
                WAITCNT(5);
            }
            __builtin_amdgcn_s_barrier();      // everyone's stage(k+1) visible
            __builtin_amdgcn_sched_barrier(0);
            Scur = Snxt;
            Snxt = Snew;
        }
    }

    // ---- reduction: wave64 shuffle -> LDS -> one atomic pair per block ----
    #pragma unroll
    for (int off = 32; off > 0; off >>= 1) {
        sq   += __shfl_down(sq, off, 64);
        cntm += __shfl_down(cntm, off, 64);
    }
    const int lane = tid & 63;
    const int wid = tid >> 6;
    if (lane == 0) { s_sq[wid] = sq; s_cnt[wid] = cntm; }
    __syncthreads();
    if (tid == 0) {
        float bsq = 0.0f, bcnt = 0.0f;
        #pragma unroll
        for (int i = 0; i < 16; ++i) { bsq += s_sq[i]; bcnt += s_cnt[i]; }
        atomicAdd(&acc[0], bsq);
        atomicAdd(&acc[1], bcnt);
        __threadfence();
        const unsigned old = atomicAdd((unsigned*)&acc[2], 1u);
        if (old == GRID - 1) {
            __threadfence();
            const float s = atomicAdd(&acc[0], 0.0f);
            const float c = atomicAdd(&acc[1], 0.0f);
            out[0] = s / fmaxf(c, 1.0f);
        }
    }
}

// ---- emergency fallback (ws too small): simple per-voxel kernel ----
__global__ __launch_bounds__(256) void warp_mse_simple(
    const float* __restrict__ mov, const float* __restrict__ vf,
    const float* __restrict__ fix, const int* __restrict__ mask,
    float* __restrict__ acc)
{
    const int idx = blockIdx.x * 256 + threadIdx.x;
    float sq = 0.0f, cnt = 0.0f;
    if (idx < NVOX) {
        const int w = idx % WW;
        const int t = idx / WW;
        const int h = t % HH;
        const int d = t / HH;
        const float z = (float)d + vf[idx];
        const float y = (float)h + vf[NVOX + idx];
        const float x = (float)w + vf[2 * NVOX + idx];
        const float z0f = floorf(z), y0f = floorf(y), x0f = floorf(x);
        const float wz = z - z0f, wy = y - y0f, wx = x - x0f;
        const int z0 = (int)z0f, y0 = (int)y0f, x0 = (int)x0f;
        const int z1 = z0 + 1, y1 = y0 + 1, x1 = x0 + 1;
        const bool zi0 = (unsigned)z0 < DD, zi1 = (unsigned)z1 < DD;
        const bool yi0 = (unsigned)y0 < HH, yi1 = (unsigned)y1 < HH;
        const bool xi0 = (unsigned)x0 < WW, xi1 = (unsigned)x1 < WW;
        auto ld = [&](int iz, int iy, int ix, bool ok) -> float {
            return ok ? mov[(iz * HH + iy) * WW + ix] : 0.0f;
        };
        const float v000 = ld(z0, y0, x0, zi0 & yi0 & xi0);
        const float v001 = ld(z0, y0, x1, zi0 & yi0 & xi1);
        const float v010 = ld(z0, y1, x0, zi0 & yi1 & xi0);
        const float v011 = ld(z0, y1, x1, zi0 & yi1 & xi1);
        const float v100 = ld(z1, y0, x0, zi1 & yi0 & xi0);
        const float v101 = ld(z1, y0, x1, zi1 & yi0 & xi1);
        const float v110 = ld(z1, y1, x0, zi1 & yi1 & xi0);
        const float v111 = ld(z1, y1, x1, zi1 & yi1 & xi1);
        const float c00 = v000 + (v001 - v000) * wx;
        const float c01 = v010 + (v011 - v010) * wx;
        const float c10 = v100 + (v101 - v100) * wx;
        const float c11 = v110 + (v111 - v110) * wx;
        const float c0 = c00 + (c01 - c00) * wy;
        const float c1 = c10 + (c11 - c10) * wy;
        const float warped = c0 + (c1 - c0) * wz;
        const float m = (mask[idx] != 0) ? 1.0f : 0.0f;
        const float diff = warped - fix[idx];
        sq = diff * diff * m;
        cnt = m;
    }
    #pragma unroll
    for (int off = 32; off > 0; off >>= 1) {
        sq  += __shfl_down(sq, off, 64);
        cnt += __shfl_down(cnt, off, 64);
    }
    __shared__ float s_sq[4], s_cnt[4];
    const int lane = threadIdx.x & 63, wid = threadIdx.x >> 6;
    if (lane == 0) { s_sq[wid] = sq; s_cnt[wid] = cnt; }
    __syncthreads();
    if (threadIdx.x == 0) {
        atomicAdd(&acc[0], s_sq[0] + s_sq[1] + s_sq[2] + s_sq[3]);
        atomicAdd(&acc[1], s_cnt[0] + s_cnt[1] + s_cnt[2] + s_cnt[3]);
    }
}

__global__ void warp_mse_finalize(const float* __restrict__ acc, float* __restrict__ out) {
    out[0] = acc[0] / fmaxf(acc[1], 1.0f);
}

extern "C" void kernel_launch(void* const* d_in, const int* in_sizes, int n_in,
                              void* d_out, int out_size, void* d_ws, size_t ws_size,
                              hipStream_t stream) {
    const float* mov  = (const float*)d_in[0];
    const float* vf   = (const float*)d_in[1];
    const float* fix  = (const float*)d_in[2];
    const int*   mask = (const int*)d_in[3];
    float* acc = (float*)d_ws;
    float* out = (float*)d_out;

    // [0,16): acc; [64,80): zero DMA source; [256,...): movh
    hipMemsetAsync(d_ws, 0, 256, stream);

    const size_t need = 256 + (size_t)NVOX * 2;
    if (ws_size >= need) {
        ushort* movh = (ushort*)((char*)d_ws + 256);
        const ushort* zbuf = (const ushort*)((char*)d_ws + 64);
        conv_fp16<<<NVOX / (256 * 8), 256, 0, stream>>>(
            (const float4*)mov, (int4*)movh);
        warp_mse_persist<<<GRID, NT, 0, stream>>>(movh, mov, vf, fix, mask,
                                                  zbuf, acc, out);
    } else {
        warp_mse_simple<<<(NVOX + 255) / 256, 256, 0, stream>>>(mov, vf, fix, mask, acc);
        warp_mse_finalize<<<1, 1, 0, stream>>>(acc, out);
    }
}

// Round 4
// 233.671 us; speedup vs baseline: 2.1828x; 1.0559x over previous
//
#include <hip/hip_runtime.h>
#include <hip/hip_fp16.h>

#define DD 192
#define HH 192
#define WW 192
#define NVOX (DD * HH * WW)

// 16x16x16 tiles, halo 8: fp16 region x32 [-8,+24), y33 [-8,+25), z33 [-8,+25)
#define RSX 32
#define RSY 33
#define RSZ 33
#define ROWD 16                    // dwords per x-row (32 halves)
#define SLABD (RSY * ROWD)         // 528 dwords per z-slab
#define RTOTH (RSX * RSY * RSZ)    // 34848 halves = 69696 B per buffer
#define RTOTD (RTOTH / 2)
#define NCHUNK (RTOTH / 8)         // 4356 16B DMA chunks
#define CHSLAB (RSY * 4)           // 132 chunks per z-slab
#define NT 1024
#define NROUND ((NCHUNK + NT - 1) / NT)   // 5 DMA rounds
#define NTILE 1728                 // 12^3
#define GRID 256                   // persistent: 1 block per CU

#define AS1 __attribute__((address_space(1)))
#define AS3 __attribute__((address_space(3)))

// counted vmcnt: loads stay in flight across raw barriers (T3/T4 pattern)
#define WAITCNT(n) asm volatile("s_waitcnt vmcnt(" #n ")" ::: "memory")

typedef float f32x4 __attribute__((ext_vector_type(4)));
typedef int   i32x4 __attribute__((ext_vector_type(4)));

// ---- mov fp32 -> fp16 (contiguous, BW-bound, runs once per launch) ----
__global__ __launch_bounds__(256) void conv_fp16(
    const float4* __restrict__ in, int4* __restrict__ out)
{
    const int i = blockIdx.x * 256 + threadIdx.x;
    const float4 a = in[2 * i];
    const float4 b = in[2 * i + 1];
    __half2 h0 = __floats2half2_rn(a.x, a.y);
    __half2 h1 = __floats2half2_rn(a.z, a.w);
    __half2 h2 = __floats2half2_rn(b.x, b.y);
    __half2 h3 = __floats2half2_rn(b.z, b.w);
    int4 o;
    o.x = *(int*)&h0; o.y = *(int*)&h1; o.z = *(int*)&h2; o.w = *(int*)&h3;
    out[i] = o;
}

struct Streams { f32x4 dz, dy, dx, f; i32x4 m; };

// octant-local tile decode: n in [0,216) -> (tx,ty,tz) inside a 6x6x6 octant,
// tz fastest (consecutive tiles share z-halo -> L2 temporal reuse)
__device__ __forceinline__ void tile_coords_oct(
    int n, int OX, int OY, int OZ, int& tx, int& ty, int& tz)
{
    const int ox = n / 36;
    const int r  = n - ox * 36;
    const int oy = r / 6;
    tx = OX + ox;
    ty = OY + oy;
    tz = OZ + (r - oy * 6);
}

// issue async DMA of one tile's fp16 region; OOB chunks redirected to zbuf.
// Per-wave vmem instruction count: 4 or 5 (round 4 is partial) — the counted
// vmcnt waits below are derived to be safe for both.
__device__ __forceinline__ void stage_tile(
    const ushort* __restrict__ movh, const ushort* __restrict__ zbuf,
    uint* sbufd, int x_lo, int y_lo, int z_lo, int tid)
{
    ushort* sbuf = (ushort*)sbufd;
    #pragma unroll
    for (int i = 0; i < NROUND; ++i) {
        const int q = tid + i * NT;
        if (q < NCHUNK) {
            const int rz = q / CHSLAB;
            const int rem = q - rz * CHSLAB;
            const int ry = rem >> 2;
            const int k  = rem & 3;
            const int gz = z_lo + rz, gy = y_lo + ry, gx = x_lo + 8 * k;
            const bool valid = ((unsigned)gz < DD) & ((unsigned)gy < HH) &
                               ((unsigned)gx < WW);
            const ushort* src = valid ? (movh + ((gz * HH + gy) * WW + gx)) : zbuf;
            const int qb = i * NT + (tid & ~63);    // wave-uniform chunk base
            __builtin_amdgcn_global_load_lds((AS1 void*)src,
                                             (AS3 void*)(sbuf + 8 * qb), 16, 0, 0);
        }
    }
}

// nontemporal: read-once streams evict-first so the XCD L2 keeps the octant's
// movh region (2.8 MB) resident for staging.
__device__ __forceinline__ Streams prefetch_streams(
    const float* __restrict__ vf, const float* __restrict__ fix,
    const int* __restrict__ mask, int base)
{
    Streams s;
    s.dz = __builtin_nontemporal_load((const f32x4*)(vf + base));
    s.dy = __builtin_nontemporal_load((const f32x4*)(vf + NVOX + base));
    s.dx = __builtin_nontemporal_load((const f32x4*)(vf + 2 * NVOX + base));
    s.f  = __builtin_nontemporal_load((const f32x4*)(fix + base));
    s.m  = __builtin_nontemporal_load((const i32x4*)(mask + base));
    return s;
}

// trilinear sample one voxel from the fp16 LDS buffer (R5/R7-proven structure)
__device__ __forceinline__ void sample_accum(
    const uint* sdw, const float* __restrict__ mov,
    int gz, int gy, int gx, float dz, float dy, float dx,
    float f, int m, int x_lo, int y_lo, int z_lo,
    float& sq, float& cnt)
{
    const float z = (float)gz + dz, y = (float)gy + dy, x = (float)gx + dx;
    const float z0f = floorf(z), y0f = floorf(y), x0f = floorf(x);
    const float wz = z - z0f, wy = y - y0f, wx = x - x0f;
    const int z0 = (int)z0f, y0 = (int)y0f, x0 = (int)x0f;
    const int z0l = z0 - z_lo, y0l = y0 - y_lo, x0l = x0 - x_lo;
    const bool inbox = ((unsigned)z0l < RSZ - 1) & ((unsigned)y0l < RSY - 1) &
                       ((unsigned)x0l < RSX - 1);

    float v000, v001, v010, v011, v100, v101, v110, v111;
    if (inbox) {
        const int o = z0l * SLABD + y0l * ROWD + (x0l >> 1);
        const bool odd = (x0l & 1) != 0;
        const uint a00 = sdw[o];
        const uint b00 = sdw[o + 1];
        const uint a01 = sdw[o + ROWD];
        const uint b01 = sdw[o + ROWD + 1];
        const uint a10 = sdw[o + SLABD];
        const uint b10 = sdw[o + SLABD + 1];
        const uint a11 = sdw[o + SLABD + ROWD];
        const uint b11 = sdw[o + SLABD + ROWD + 1];
        auto pr = [&](uint A, uint B, float& l, float& r) {
            const float2 fa = __half22float2(*(const __half2*)&A);
            const float fb = __low2float(*(const __half2*)&B);
            l = odd ? fa.y : fa.x;
            r = odd ? fb   : fa.y;
        };
        pr(a00, b00, v000, v001);
        pr(a01, b01, v010, v011);
        pr(a10, b10, v100, v101);
        pr(a11, b11, v110, v111);
    } else {
        // rare (~2% of voxels): beyond halo — fp32 global fallback
        const int z1 = z0 + 1, y1 = y0 + 1, x1 = x0 + 1;
        const bool zi0 = (unsigned)z0 < DD, zi1 = (unsigned)z1 < DD;
        const bool yi0 = (unsigned)y0 < HH, yi1 = (unsigned)y1 < HH;
        const bool xi0 = (unsigned)x0 < WW, xi1 = (unsigned)x1 < WW;
        auto ld = [&](int iz, int iy, int ix, bool ok) -> float {
            return ok ? mov[(iz * HH + iy) * WW + ix] : 0.0f;
        };
        v000 = ld(z0, y0, x0, zi0 & yi0 & xi0);
        v001 = ld(z0, y0, x1, zi0 & yi0 & xi1);
        v010 = ld(z0, y1, x0, zi0 & yi1 & xi0);
        v011 = ld(z0, y1, x1, zi0 & yi1 & xi1);
        v100 = ld(z1, y0, x0, zi1 & yi0 & xi0);
        v101 = ld(z1, y0, x1, zi1 & yi0 & xi1);
        v110 = ld(z1, y1, x0, zi1 & yi1 & xi0);
        v111 = ld(z1, y1, x1, zi1 & yi1 & xi1);
    }

    const float c00 = v000 + (v001 - v000) * wx;
    const float c01 = v010 + (v011 - v010) * wx;
    const float c10 = v100 + (v101 - v100) * wx;
    const float c11 = v110 + (v111 - v110) * wx;
    const float c0 = c00 + (c01 - c00) * wy;
    const float c1 = c10 + (c11 - c10) * wy;
    const float warped = c0 + (c1 - c0) * wz;

    const float mm = (m != 0) ? 1.0f : 0.0f;
    const float diff = warped - f;
    sq += diff * diff * mm;
    cnt += mm;
}

// ---- persistent pipelined kernel: double-buffered LDS, counted-vmcnt,
// XCD-octant tile partition ----
// Block b runs on XCD b&7 (HW round-robin, m09). XCD k owns the 6x6x6 tile
// octant whose origin bits come from k: movh footprint (96+2*8)^3 * 2B =
// 2.8 MB < 4 MB XCD L2, so staging re-reads hit the local L2 (~200 cy)
// instead of L3/HBM (~900 cy) — lifts the outstanding-limited staging BW.
__global__ __launch_bounds__(NT) void warp_mse_persist(
    const ushort* __restrict__ movh,
    const float* __restrict__ mov,
    const float* __restrict__ vf,
    const float* __restrict__ fix,
    const int* __restrict__ mask,
    const ushort* __restrict__ zbuf,
    float* __restrict__ acc,   // [0]=sum(sq*m), [1]=sum(m), [2]=done ctr
    float* __restrict__ out)
{
    __shared__ uint sbufd[2][RTOTD];   // 2 x 69.7 KB fp16 regions
    __shared__ float s_sq[16], s_cnt[16];

    const int tid = threadIdx.x;
    const int b = blockIdx.x;
    const int xcd = b & 7;             // HW XCD assignment
    const int w   = b >> 3;            // 0..31: CU index within the XCD
    // 216 octant tiles over 32 blocks: w<24 take 7 tiles, rest take 6
    const int start = w * 6 + min(w, 24);
    const int cnt_t = 6 + (w < 24 ? 1 : 0);
    const int OX = (xcd & 1) * 6;
    const int OY = ((xcd >> 1) & 1) * 6;
    const int OZ = ((xcd >> 2) & 1) * 6;

    // thread -> x-quad: lxg (tid&3)*4, ly (tid>>2)&15, lz tid>>6
    const int lxg = (tid & 3) * 4;
    const int ly  = (tid >> 2) & 15;
    const int lz  = tid >> 6;

    float sq = 0.0f, cntm = 0.0f;

    // ---- prologue: stage tiles start, start+1; streams for both ----
    int tx, ty, tz;
    tile_coords_oct(start, OX, OY, OZ, tx, ty, tz);
    stage_tile(movh, zbuf, sbufd[0], tx * 16 - 8, ty * 16 - 8, tz * 16 - 8, tid);
    Streams Scur = prefetch_streams(vf, fix, mask,
        ((tz * 16 + lz) * HH + ty * 16 + ly) * WW + tx * 16 + lxg);
    Streams Snxt = Scur;
    if (cnt_t > 1) {
        int nx, ny, nz;
        tile_coords_oct(start + 1, OX, OY, OZ, nx, ny, nz);
        stage_tile(movh, zbuf, sbufd[1], nx * 16 - 8, ny * 16 - 8, nz * 16 - 8, tid);
        Snxt = prefetch_streams(vf, fix, mask,
            ((nz * 16 + lz) * HH + ny * 16 + ly) * WW + nx * 16 + lxg);
        // issued after stage(0): streams(0)[5] + stage(1)[>=4] + streams(1)[5] >= 14
        WAITCNT(14);
    } else {
        WAITCNT(5);
    }
    __builtin_amdgcn_s_barrier();
    __builtin_amdgcn_sched_barrier(0);

    for (int k = 0; k < cnt_t; ++k) {
        const int cur = k & 1;
        int cx, cy, cz;
        tile_coords_oct(start + k, OX, OY, OZ, cx, cy, cz);
        const int x_lo = cx * 16 - 8, y_lo = cy * 16 - 8, z_lo = cz * 16 - 8;
        const int gz = cz * 16 + lz, gy = cy * 16 + ly, gx0 = cx * 16 + lxg;
        const uint* sdw = sbufd[cur];

        sample_accum(sdw, mov, gz, gy, gx0,     Scur.dz.x, Scur.dy.x, Scur.dx.x,
                     Scur.f.x, Scur.m.x, x_lo, y_lo, z_lo, sq, cntm);
        sample_accum(sdw, mov, gz, gy, gx0 + 1, Scur.dz.y, Scur.dy.y, Scur.dx.y,
                     Scur.f.y, Scur.m.y, x_lo, y_lo, z_lo, sq, cntm);
        sample_accum(sdw, mov, gz, gy, gx0 + 2, Scur.dz.z, Scur.dy.z, Scur.dx.z,
                     Scur.f.z, Scur.m.z, x_lo, y_lo, z_lo, sq, cntm);
        sample_accum(sdw, mov, gz, gy, gx0 + 3, Scur.dz.w, Scur.dy.w, Scur.dx.w,
                     Scur.f.w, Scur.m.w, x_lo, y_lo, z_lo, sq, cntm);

        if (k + 1 < cnt_t) {
            __builtin_amdgcn_sched_barrier(0);
            __builtin_amdgcn_s_barrier();      // all waves done reading sbufd[cur]
            Streams Snew = Snxt;
            if (k + 2 < cnt_t) {
                int nx, ny, nz;
                tile_coords_oct(start + k + 2, OX, OY, OZ, nx, ny, nz);
                // issue k+2 DMA + streams FIRST, then wait only for k+1:
                stage_tile(movh, zbuf, sbufd[cur],
                           nx * 16 - 8, ny * 16 - 8, nz * 16 - 8, tid);
                Snew = prefetch_streams(vf, fix, mask,
                    ((nz * 16 + lz) * HH + ny * 16 + ly) * WW + nx * 16 + lxg);
                // issued after stage(k+1): streams(k+1)[5] + stage(k+2)[>=4]
                //                        + streams(k+2)[5] >= 14
                WAITCNT(14);
            } else {
                // issued after stage(k+1): streams(k+1)[5]
                WAITCNT(5);
            }
            __builtin_amdgcn_s_barrier();      // everyone's stage(k+1) visible
            __builtin_amdgcn_sched_barrier(0);
            Scur = Snxt;
            Snxt = Snew;
        }
    }

    // ---- reduction: wave64 shuffle -> LDS -> one atomic pair per block ----
    #pragma unroll
    for (int off = 32; off > 0; off >>= 1) {
        sq   += __shfl_down(sq, off, 64);
        cntm += __shfl_down(cntm, off, 64);
    }
    const int lane = tid & 63;
    const int wid = tid >> 6;
    if (lane == 0) { s_sq[wid] = sq; s_cnt[wid] = cntm; }
    __syncthreads();
    if (tid == 0) {
        float bsq = 0.0f, bcnt = 0.0f;
        #pragma unroll
        for (int i = 0; i < 16; ++i) { bsq += s_sq[i]; bcnt += s_cnt[i]; }
        atomicAdd(&acc[0], bsq);
        atomicAdd(&acc[1], bcnt);
        __threadfence();
        const unsigned old = atomicAdd((unsigned*)&acc[2], 1u);
        if (old == GRID - 1) {
            __threadfence();
            const float s = atomicAdd(&acc[0], 0.0f);
            const float c = atomicAdd(&acc[1], 0.0f);
            out[0] = s / fmaxf(c, 1.0f);
        }
    }
}

// ---- emergency fallback (ws too small): simple per-voxel kernel ----
__global__ __launch_bounds__(256) void warp_mse_simple(
    const float* __restrict__ mov, const float* __restrict__ vf,
    const float* __restrict__ fix, const int* __restrict__ mask,
    float* __restrict__ acc)
{
    const int idx = blockIdx.x * 256 + threadIdx.x;
    float sq = 0.0f, cnt = 0.0f;
    if (idx < NVOX) {
        const int w = idx % WW;
        const int t = idx / WW;
        const int h = t % HH;
        const int d = t / HH;
        const float z = (float)d + vf[idx];
        const float y = (float)h + vf[NVOX + idx];
        const float x = (float)w + vf[2 * NVOX + idx];
        const float z0f = floorf(z), y0f = floorf(y), x0f = floorf(x);
        const float wz = z - z0f, wy = y - y0f, wx = x - x0f;
        const int z0 = (int)z0f, y0 = (int)y0f, x0 = (int)x0f;
        const int z1 = z0 + 1, y1 = y0 + 1, x1 = x0 + 1;
        const bool zi0 = (unsigned)z0 < DD, zi1 = (unsigned)z1 < DD;
        const bool yi0 = (unsigned)y0 < HH, yi1 = (unsigned)y1 < HH;
        const bool xi0 = (unsigned)x0 < WW, xi1 = (unsigned)x1 < WW;
        auto ld = [&](int iz, int iy, int ix, bool ok) -> float {
            return ok ? mov[(iz * HH + iy) * WW + ix] : 0.0f;
        };
        const float v000 = ld(z0, y0, x0, zi0 & yi0 & xi0);
        const float v001 = ld(z0, y0, x1, zi0 & yi0 & xi1);
        const float v010 = ld(z0, y1, x0, zi0 & yi1 & xi0);
        const float v011 = ld(z0, y1, x1, zi0 & yi1 & xi1);
        const float v100 = ld(z1, y0, x0, zi1 & yi0 & xi0);
        const float v101 = ld(z1, y0, x1, zi1 & yi0 & xi1);
        const float v110 = ld(z1, y1, x0, zi1 & yi1 & xi0);
        const float v111 = ld(z1, y1, x1, zi1 & yi1 & xi1);
        const float c00 = v000 + (v001 - v000) * wx;
        const float c01 = v010 + (v011 - v010) * wx;
        const float c10 = v100 + (v101 - v100) * wx;
        const float c11 = v110 + (v111 - v110) * wx;
        const float c0 = c00 + (c01 - c00) * wy;
        const float c1 = c10 + (c11 - c10) * wy;
        const float warped = c0 + (c1 - c0) * wz;
        const float m = (mask[idx] != 0) ? 1.0f : 0.0f;
        const float diff = warped - fix[idx];
        sq = diff * diff * m;
        cnt = m;
    }
    #pragma unroll
    for (int off = 32; off > 0; off >>= 1) {
        sq  += __shfl_down(sq, off, 64);
        cnt += __shfl_down(cnt, off, 64);
    }
    __shared__ float s_sq[4], s_cnt[4];
    const int lane = threadIdx.x & 63, wid = threadIdx.x >> 6;
    if (lane == 0) { s_sq[wid] = sq; s_cnt[wid] = cnt; }
    __syncthreads();
    if (threadIdx.x == 0) {
        atomicAdd(&acc[0], s_sq[0] + s_sq[1] + s_sq[2] + s_sq[3]);
        atomicAdd(&acc[1], s_cnt[0] + s_cnt[1] + s_cnt[2] + s_cnt[3]);
    }
}

__global__ void warp_mse_finalize(const float* __restrict__ acc, float* __restrict__ out) {
    out[0] = acc[0] / fmaxf(acc[1], 1.0f);
}

extern "C" void kernel_launch(void* const* d_in, const int* in_sizes, int n_in,
                              void* d_out, int out_size, void* d_ws, size_t ws_size,
                              hipStream_t stream) {
    const float* mov  = (const float*)d_in[0];
    const float* vf   = (const float*)d_in[1];
    const float* fix  = (const float*)d_in[2];
    const int*   mask = (const int*)d_in[3];
    float* acc = (float*)d_ws;
    float* out = (float*)d_out;

    // [0,16): acc; [64,80): zero DMA source; [256,...): movh
    hipMemsetAsync(d_ws, 0, 256, stream);

    const size_t need = 256 + (size_t)NVOX * 2;
    if (ws_size >= need) {
        ushort* movh = (ushort*)((char*)d_ws + 256);
        const ushort* zbuf = (const ushort*)((char*)d_ws + 64);
        conv_fp16<<<NVOX / (256 * 8), 256, 0, stream>>>(
            (const float4*)mov, (int4*)movh);
        warp_mse_persist<<<GRID, NT, 0, stream>>>(movh, mov, vf, fix, mask,
                                                  zbuf, acc, out);
    } else {
        warp_mse_simple<<<(NVOX + 255) / 256, 256, 0, stream>>>(mov, vf, fix, mask, acc);
        warp_mse_finalize<<<1, 1, 0, stream>>>(acc, out);
    }
}

// Round 5
// 217.189 us; speedup vs baseline: 2.3484x; 1.0759x over previous
//
#include <hip/hip_runtime.h>
#include <hip/hip_fp16.h>

#define DD 192
#define HH 192
#define WW 192
#define NVOX (DD * HH * WW)

// 32x16x8 tiles, halo 8: fp16 region x48 [-8,+40), y33 [-8,+25), z25 [-8,+17)
// Tile is 32 wide in x so one wave's stream loads form 128-B full-line
// segments (8 lanes x float4) — doubles bytes per in-flight-segment slot.
#define TX 32
#define TY 16
#define TZ 8
#define RSX 48
#define RSY 33
#define RSZ 25
#define ROWD 24                    // dwords per x-row (48 halves)
#define SLABD (RSY * ROWD)         // 792 dwords per z-slab
#define RTOTH (RSX * RSY * RSZ)    // 39600 halves = 79200 B per buffer
#define RTOTD (RTOTH / 2)          // 19800 dwords
#define NCHUNK (RTOTH / 8)         // 4950 16B DMA chunks
#define CHROW 6                    // chunks per x-row
#define CHSLAB (RSY * CHROW)       // 198 chunks per z-slab
#define NT 1024
#define NROUND ((NCHUNK + NT - 1) / NT)   // 5 DMA rounds
#define GRID 256                   // persistent: 1 block per CU

#define AS1 __attribute__((address_space(1)))
#define AS3 __attribute__((address_space(3)))

// counted vmcnt: loads stay in flight across raw barriers (T3/T4 pattern)
#define WAITCNT(n) asm volatile("s_waitcnt vmcnt(" #n ")" ::: "memory")

typedef float f32x4 __attribute__((ext_vector_type(4)));
typedef int   i32x4 __attribute__((ext_vector_type(4)));

// ---- mov fp32 -> fp16 (contiguous, BW-bound, runs once per launch) ----
__global__ __launch_bounds__(256) void conv_fp16(
    const float4* __restrict__ in, int4* __restrict__ out)
{
    const int i = blockIdx.x * 256 + threadIdx.x;
    const float4 a = in[2 * i];
    const float4 b = in[2 * i + 1];
    __half2 h0 = __floats2half2_rn(a.x, a.y);
    __half2 h1 = __floats2half2_rn(a.z, a.w);
    __half2 h2 = __floats2half2_rn(b.x, b.y);
    __half2 h3 = __floats2half2_rn(b.z, b.w);
    int4 o;
    o.x = *(int*)&h0; o.y = *(int*)&h1; o.z = *(int*)&h2; o.w = *(int*)&h3;
    out[i] = o;
}

struct Streams { f32x4 dz, dy, dx, f; i32x4 m; };

// octant-local tile decode: n in [0,216) -> tile (tx,ty,tz) inside a
// 3x6x12 tile-octant, tz fastest (consecutive tiles share z-halo -> L2 reuse)
__device__ __forceinline__ void tile_coords_oct(
    int n, int OX, int OY, int OZ, int& tx, int& ty, int& tz)
{
    const int ox = n / 72;
    const int r  = n - ox * 72;
    const int oy = r / 12;
    tx = OX + ox;
    ty = OY + oy;
    tz = OZ + (r - oy * 12);
}

// issue async DMA of one tile's fp16 region; OOB chunks redirected to zbuf.
// Per-wave vmem instruction count: 4 or 5 — counted vmcnt below covers both.
__device__ __forceinline__ void stage_tile(
    const ushort* __restrict__ movh, const ushort* __restrict__ zbuf,
    uint* sbufd, int x_lo, int y_lo, int z_lo, int tid)
{
    ushort* sbuf = (ushort*)sbufd;
    #pragma unroll
    for (int i = 0; i < NROUND; ++i) {
        const int q = tid + i * NT;
        if (q < NCHUNK) {
            const int rz = q / CHSLAB;
            const int rem = q - rz * CHSLAB;
            const int ry = rem / CHROW;
            const int k  = rem - ry * CHROW;
            const int gz = z_lo + rz, gy = y_lo + ry, gx = x_lo + 8 * k;
            const bool valid = ((unsigned)gz < DD) & ((unsigned)gy < HH) &
                               ((unsigned)gx < WW);
            const ushort* src = valid ? (movh + ((gz * HH + gy) * WW + gx)) : zbuf;
            const int qb = i * NT + (tid & ~63);    // wave-uniform chunk base
            __builtin_amdgcn_global_load_lds((AS1 void*)src,
                                             (AS3 void*)(sbuf + 8 * qb), 16, 0, 0);
        }
    }
}

// nontemporal: read-once streams evict-first so the XCD L2 keeps the octant's
// movh region (2.8 MB) resident for staging.
__device__ __forceinline__ Streams prefetch_streams(
    const float* __restrict__ vf, const float* __restrict__ fix,
    const int* __restrict__ mask, int base)
{
    Streams s;
    s.dz = __builtin_nontemporal_load((const f32x4*)(vf + base));
    s.dy = __builtin_nontemporal_load((const f32x4*)(vf + NVOX + base));
    s.dx = __builtin_nontemporal_load((const f32x4*)(vf + 2 * NVOX + base));
    s.f  = __builtin_nontemporal_load((const f32x4*)(fix + base));
    s.m  = __builtin_nontemporal_load((const i32x4*)(mask + base));
    return s;
}

// trilinear sample one voxel from the fp16 LDS buffer
__device__ __forceinline__ void sample_accum(
    const uint* sdw, const ushort* __restrict__ movh,
    int gz, int gy, int gx, float dz, float dy, float dx,
    float f, int m, int x_lo, int y_lo, int z_lo,
    float& sq, float& cnt)
{
    const float z = (float)gz + dz, y = (float)gy + dy, x = (float)gx + dx;
    const float z0f = floorf(z), y0f = floorf(y), x0f = floorf(x);
    const float wz = z - z0f, wy = y - y0f, wx = x - x0f;
    const int z0 = (int)z0f, y0 = (int)y0f, x0 = (int)x0f;
    const int z0l = z0 - z_lo, y0l = y0 - y_lo, x0l = x0 - x_lo;
    const bool inbox = ((unsigned)z0l < RSZ - 1) & ((unsigned)y0l < RSY - 1) &
                       ((unsigned)x0l < RSX - 1);

    float v000, v001, v010, v011, v100, v101, v110, v111;
    if (inbox) {
        const int o = z0l * SLABD + y0l * ROWD + (x0l >> 1);
        const bool odd = (x0l & 1) != 0;
        const uint a00 = sdw[o];
        const uint b00 = sdw[o + 1];
        const uint a01 = sdw[o + ROWD];
        const uint b01 = sdw[o + ROWD + 1];
        const uint a10 = sdw[o + SLABD];
        const uint b10 = sdw[o + SLABD + 1];
        const uint a11 = sdw[o + SLABD + ROWD];
        const uint b11 = sdw[o + SLABD + ROWD + 1];
        auto pr = [&](uint A, uint B, float& l, float& r) {
            const float2 fa = __half22float2(*(const __half2*)&A);
            const float fb = __low2float(*(const __half2*)&B);
            l = odd ? fa.y : fa.x;
            r = odd ? fb   : fa.y;
        };
        pr(a00, b00, v000, v001);
        pr(a01, b01, v010, v011);
        pr(a10, b10, v100, v101);
        pr(a11, b11, v110, v111);
    } else {
        // rare (~1% of voxels): beyond halo — clamp+mask gather from movh,
        // which is XCD-L2-resident (octant region) -> ~200cy, not HBM.
        const int z1 = z0 + 1, y1 = y0 + 1, x1 = x0 + 1;
        const bool zi0 = (unsigned)z0 < DD, zi1 = (unsigned)z1 < DD;
        const bool yi0 = (unsigned)y0 < HH, yi1 = (unsigned)y1 < HH;
        const bool xi0 = (unsigned)x0 < WW, xi1 = (unsigned)x1 < WW;
        const int zc0 = min(max(z0, 0), DD - 1), zc1 = min(max(z1, 0), DD - 1);
        const int yc0 = min(max(y0, 0), HH - 1), yc1 = min(max(y1, 0), HH - 1);
        const int xc0 = min(max(x0, 0), WW - 1), xc1 = min(max(x1, 0), WW - 1);
        const int r00 = (zc0 * HH + yc0) * WW;
        const int r01 = (zc0 * HH + yc1) * WW;
        const int r10 = (zc1 * HH + yc0) * WW;
        const int r11 = (zc1 * HH + yc1) * WW;
        v000 = (zi0 & yi0 & xi0) ? __half2float(((const __half*)movh)[r00 + xc0]) : 0.0f;
        v001 = (zi0 & yi0 & xi1) ? __half2float(((const __half*)movh)[r00 + xc1]) : 0.0f;
        v010 = (zi0 & yi1 & xi0) ? __half2float(((const __half*)movh)[r01 + xc0]) : 0.0f;
        v011 = (zi0 & yi1 & xi1) ? __half2float(((const __half*)movh)[r01 + xc1]) : 0.0f;
        v100 = (zi1 & yi0 & xi0) ? __half2float(((const __half*)movh)[r10 + xc0]) : 0.0f;
        v101 = (zi1 & yi0 & xi1) ? __half2float(((const __half*)movh)[r10 + xc1]) : 0.0f;
        v110 = (zi1 & yi1 & xi0) ? __half2float(((const __half*)movh)[r11 + xc0]) : 0.0f;
        v111 = (zi1 & yi1 & xi1) ? __half2float(((const __half*)movh)[r11 + xc1]) : 0.0f;
    }

    const float c00 = v000 + (v001 - v000) * wx;
    const float c01 = v010 + (v011 - v010) * wx;
    const float c10 = v100 + (v101 - v100) * wx;
    const float c11 = v110 + (v111 - v110) * wx;
    const float c0 = c00 + (c01 - c00) * wy;
    const float c1 = c10 + (c11 - c10) * wy;
    const float warped = c0 + (c1 - c0) * wz;

    const float mm = (m != 0) ? 1.0f : 0.0f;
    const float diff = warped - f;
    sq += diff * diff * mm;
    cnt += mm;
}

// ---- persistent pipelined kernel: double-buffered LDS, counted-vmcnt,
// XCD-octant partition, 32-wide tiles for full-line stream segments ----
__global__ __launch_bounds__(NT) void warp_mse_persist(
    const ushort* __restrict__ movh,
    const float* __restrict__ mov,   // unused (kept for signature stability)
    const float* __restrict__ vf,
    const float* __restrict__ fix,
    const int* __restrict__ mask,
    const ushort* __restrict__ zbuf,
    float* __restrict__ acc,   // [0]=sum(sq*m), [1]=sum(m), [2]=done ctr
    float* __restrict__ out)
{
    __shared__ uint sbufd[2][RTOTD + 8];   // 2 x 79.2 KB (+pad for benign o+1 reads)
    __shared__ float s_sq[16], s_cnt[16];

    const int tid = threadIdx.x;
    const int b = blockIdx.x;
    const int xcd = b & 7;             // HW XCD assignment (round-robin, m09)
    const int w   = b >> 3;            // 0..31: CU index within the XCD
    // 216 octant tiles over 32 blocks: w<24 take 7 tiles, rest take 6
    const int start = w * 6 + min(w, 24);
    const int cnt_t = 6 + (w < 24 ? 1 : 0);
    const int OX = (xcd & 1) * 3;
    const int OY = ((xcd >> 1) & 1) * 6;
    const int OZ = ((xcd >> 2) & 1) * 12;

    // thread -> x-quad: 8 lanes span 32 x (128-B stream segments)
    const int lxg = (tid & 7) * 4;
    const int ly  = (tid >> 3) & 15;
    const int lz  = tid >> 7;

    float sq = 0.0f, cntm = 0.0f;

    // ---- prologue: stage tiles start, start+1; streams for both ----
    int tx, ty, tz;
    tile_coords_oct(start, OX, OY, OZ, tx, ty, tz);
    stage_tile(movh, zbuf, sbufd[0], tx * TX - 8, ty * TY - 8, tz * TZ - 8, tid);
    Streams Scur = prefetch_streams(vf, fix, mask,
        ((tz * TZ + lz) * HH + ty * TY + ly) * WW + tx * TX + lxg);
    Streams Snxt = Scur;
    if (cnt_t > 1) {
        int nx, ny, nz;
        tile_coords_oct(start + 1, OX, OY, OZ, nx, ny, nz);
        stage_tile(movh, zbuf, sbufd[1], nx * TX - 8, ny * TY - 8, nz * TZ - 8, tid);
        Snxt = prefetch_streams(vf, fix, mask,
            ((nz * TZ + lz) * HH + ny * TY + ly) * WW + nx * TX + lxg);
        // issued after stage(0): streams(0)[5] + stage(1)[>=4] + streams(1)[5] >= 14
        WAITCNT(14);
    } else {
        WAITCNT(5);
    }
    __builtin_amdgcn_s_barrier();
    __builtin_amdgcn_sched_barrier(0);

    for (int k = 0; k < cnt_t; ++k) {
        const int cur = k & 1;
        int cx, cy, cz;
        tile_coords_oct(start + k, OX, OY, OZ, cx, cy, cz);
        const int x_lo = cx * TX - 8, y_lo = cy * TY - 8, z_lo = cz * TZ - 8;
        const int gz = cz * TZ + lz, gy = cy * TY + ly, gx0 = cx * TX + lxg;
        const uint* sdw = sbufd[cur];

        sample_accum(sdw, movh, gz, gy, gx0,     Scur.dz.x, Scur.dy.x, Scur.dx.x,
                     Scur.f.x, Scur.m.x, x_lo, y_lo, z_lo, sq, cntm);
        sample_accum(sdw, movh, gz, gy, gx0 + 1, Scur.dz.y, Scur.dy.y, Scur.dx.y,
                     Scur.f.y, Scur.m.y, x_lo, y_lo, z_lo, sq, cntm);
        sample_accum(sdw, movh, gz, gy, gx0 + 2, Scur.dz.z, Scur.dy.z, Scur.dx.z,
                     Scur.f.z, Scur.m.z, x_lo, y_lo, z_lo, sq, cntm);
        sample_accum(sdw, movh, gz, gy, gx0 + 3, Scur.dz.w, Scur.dy.w, Scur.dx.w,
                     Scur.f.w, Scur.m.w, x_lo, y_lo, z_lo, sq, cntm);

        if (k + 1 < cnt_t) {
            __builtin_amdgcn_sched_barrier(0);
            __builtin_amdgcn_s_barrier();      // all waves done reading sbufd[cur]
            Streams Snew = Snxt;
            if (k + 2 < cnt_t) {
                int nx, ny, nz;
                tile_coords_oct(start + k + 2, OX, OY, OZ, nx, ny, nz);
                // issue k+2 DMA + streams FIRST, then wait only for k+1:
                stage_tile(movh, zbuf, sbufd[cur],
                           nx * TX - 8, ny * TY - 8, nz * TZ - 8, tid);
                Snew = prefetch_streams(vf, fix, mask,
                    ((nz * TZ + lz) * HH + ny * TY + ly) * WW + nx * TX + lxg);
                // issued after stage(k+1): streams(k+1)[5] + stage(k+2)[>=4]
                //                        + streams(k+2)[5] >= 14
                WAITCNT(14);
            } else {
                // issued after stage(k+1): streams(k+1)[5]
                WAITCNT(5);
            }
            __builtin_amdgcn_s_barrier();      // everyone's stage(k+1) visible
            __builtin_amdgcn_sched_barrier(0);
            Scur = Snxt;
            Snxt = Snew;
        }
    }

    // ---- reduction: wave64 shuffle -> LDS -> one atomic pair per block ----
    #pragma unroll
    for (int off = 32; off > 0; off >>= 1) {
        sq   += __shfl_down(sq, off, 64);
        cntm += __shfl_down(cntm, off, 64);
    }
    const int lane = tid & 63;
    const int wid = tid >> 6;
    if (lane == 0) { s_sq[wid] = sq; s_cnt[wid] = cntm; }
    __syncthreads();
    if (tid == 0) {
        float bsq = 0.0f, bcnt = 0.0f;
        #pragma unroll
        for (int i = 0; i < 16; ++i) { bsq += s_sq[i]; bcnt += s_cnt[i]; }
        atomicAdd(&acc[0], bsq);
        atomicAdd(&acc[1], bcnt);
        __threadfence();
        const unsigned old = atomicAdd((unsigned*)&acc[2], 1u);
        if (old == GRID - 1) {
            __threadfence();
            const float s = atomicAdd(&acc[0], 0.0f);
            const float c = atomicAdd(&acc[1], 0.0f);
            out[0] = s / fmaxf(c, 1.0f);
        }
    }
}

// ---- emergency fallback (ws too small): simple per-voxel kernel ----
__global__ __launch_bounds__(256) void warp_mse_simple(
    const float* __restrict__ mov, const float* __restrict__ vf,
    const float* __restrict__ fix, const int* __restrict__ mask,
    float* __restrict__ acc)
{
    const int idx = blockIdx.x * 256 + threadIdx.x;
    float sq = 0.0f, cnt = 0.0f;
    if (idx < NVOX) {
        const int w = idx % WW;
        const int t = idx / WW;
        const int h = t % HH;
        const int d = t / HH;
        const float z = (float)d + vf[idx];
        const float y = (float)h + vf[NVOX + idx];
        const float x = (float)w + vf[2 * NVOX + idx];
        const float z0f = floorf(z), y0f = floorf(y), x0f = floorf(x);
        const float wz = z - z0f, wy = y - y0f, wx = x - x0f;
        const int z0 = (int)z0f, y0 = (int)y0f, x0 = (int)x0f;
        const int z1 = z0 + 1, y1 = y0 + 1, x1 = x0 + 1;
        const bool zi0 = (unsigned)z0 < DD, zi1 = (unsigned)z1 < DD;
        const bool yi0 = (unsigned)y0 < HH, yi1 = (unsigned)y1 < HH;
        const bool xi0 = (unsigned)x0 < WW, xi1 = (unsigned)x1 < WW;
        auto ld = [&](int iz, int iy, int ix, bool ok) -> float {
            return ok ? mov[(iz * HH + iy) * WW + ix] : 0.0f;
        };
        const float v000 = ld(z0, y0, x0, zi0 & yi0 & xi0);
        const float v001 = ld(z0, y0, x1, zi0 & yi0 & xi1);
        const float v010 = ld(z0, y1, x0, zi0 & yi1 & xi0);
        const float v011 = ld(z0, y1, x1, zi0 & yi1 & xi1);
        const float v100 = ld(z1, y0, x0, zi1 & yi0 & xi0);
        const float v101 = ld(z1, y0, x1, zi1 & yi0 & xi1);
        const float v110 = ld(z1, y1, x0, zi1 & yi1 & xi0);
        const float v111 = ld(z1, y1, x1, zi1 & yi1 & xi1);
        const float c00 = v000 + (v001 - v000) * wx;
        const float c01 = v010 + (v011 - v010) * wx;
        const float c10 = v100 + (v101 - v100) * wx;
        const float c11 = v110 + (v111 - v110) * wx;
        const float c0 = c00 + (c01 - c00) * wy;
        const float c1 = c10 + (c11 - c10) * wy;
        const float warped = c0 + (c1 - c0) * wz;
        const float m = (mask[idx] != 0) ? 1.0f : 0.0f;
        const float diff = warped - fix[idx];
        sq = diff * diff * m;
        cnt = m;
    }
    #pragma unroll
    for (int off = 32; off > 0; off >>= 1) {
        sq  += __shfl_down(sq, off, 64);
        cnt += __shfl_down(cnt, off, 64);
    }
    __shared__ float s_sq[4], s_cnt[4];
    const int lane = threadIdx.x & 63, wid = threadIdx.x >> 6;
    if (lane == 0) { s_sq[wid] = sq; s_cnt[wid] = cnt; }
    __syncthreads();
    if (threadIdx.x == 0) {
        atomicAdd(&acc[0], s_sq[0] + s_sq[1] + s_sq[2] + s_sq[3]);
        atomicAdd(&acc[1], s_cnt[0] + s_cnt[1] + s_cnt[2] + s_cnt[3]);
    }
}

__global__ void warp_mse_finalize(const float* __restrict__ acc, float* __restrict__ out) {
    out[0] = acc[0] / fmaxf(acc[1], 1.0f);
}

extern "C" void kernel_launch(void* const* d_in, const int* in_sizes, int n_in,
                              void* d_out, int out_size, void* d_ws, size_t ws_size,
                              hipStream_t stream) {
    const float* mov  = (const float*)d_in[0];
    const float* vf   = (const float*)d_in[1];
    const float* fix  = (const float*)d_in[2];
    const int*   mask = (const int*)d_in[3];
    float* acc = (float*)d_ws;
    float* out = (float*)d_out;

    // [0,16): acc; [64,80): zero DMA source; [256,...): movh
    hipMemsetAsync(d_ws, 0, 256, stream);

    const size_t need = 256 + (size_t)NVOX * 2;
    if (ws_size >= need) {
        ushort* movh = (ushort*)((char*)d_ws + 256);
        const ushort* zbuf = (const ushort*)((char*)d_ws + 64);
        conv_fp16<<<NVOX / (256 * 8), 256, 0, stream>>>(
            (const float4*)mov, (int4*)movh);
        warp_mse_persist<<<GRID, NT, 0, stream>>>(movh, mov, vf, fix, mask,
                                                  zbuf, acc, out);
    } else {
        warp_mse_simple<<<(NVOX + 255) / 256, 256, 0, stream>>>(mov, vf, fix, mask, acc);
        warp_mse_finalize<<<1, 1, 0, stream>>>(acc, out);
    }
}